// Round 9
// baseline (247.668 us; speedup 1.0000x reference)
//
#include <hip/hip_runtime.h>

// FeatureMagnet r8: dispatch-count attack. 12 dispatches (was 15):
//  - k_match now also does the prefix-scan (remain) in the same block
//  - staging kernels deleted: GEMMs read fp32 weights/activations directly,
//    packing bf16 inline (concat/gather folded into GEMM A-loads)
//  - finalize_q folded into MLP3 epilogue (+gather blocks)
// Attention identical to r7 (LDS-staged K/V, KSPLIT=4, exp2 softmax).
// LE=LA=2048, C=256, H=8, DH=32, DF=1024, n_remain=1024, Lq=3072, Lk=4096.

#define LE 2048
#define LA 2048
#define CDIM 256
#define HN 8
#define DH 32
#define DFF 1024
#define NREM 1024
#define LQC 3072
#define LKC 4096
#define KSPLIT 4
#define NIT (LKC / KSPLIT / 64)

typedef unsigned short u16;
typedef unsigned int u32;
typedef __attribute__((ext_vector_type(8))) short bf16x8;
typedef __attribute__((ext_vector_type(4))) float f32x4;

__device__ __forceinline__ u32 pk_bf16(float a, float b) {
    u32 ua = (__builtin_bit_cast(u32, a) + 0x8000u) >> 16;
    u32 ub = (__builtin_bit_cast(u32, b) + 0x8000u) >> 16;
    return ua | (ub << 16);
}
__device__ __forceinline__ u16 bf16_1(float a) {
    return (u16)((__builtin_bit_cast(u32, a) + 0x8000u) >> 16);
}
__device__ __forceinline__ float fast_exp2(float x) {
    return __builtin_amdgcn_exp2f(x);
}
// load 8 consecutive fp32, round to bf16x8
__device__ __forceinline__ bf16x8 pk8(const float* p) {
    float4 f0 = *(const float4*)p;
    float4 f1 = *(const float4*)(p + 4);
    union { u32 u[4]; bf16x8 v; } r;
    r.u[0] = pk_bf16(f0.x, f0.y); r.u[1] = pk_bf16(f0.z, f0.w);
    r.u[2] = pk_bf16(f1.x, f1.y); r.u[3] = pk_bf16(f1.z, f1.w);
    return r.v;
}

// --------------------- hash-join matching + remain scan (one block) --------
__global__ __launch_bounds__(1024) void k_match(const int* __restrict__ pos_ego,
                                                const int* __restrict__ pos_agent,
                                                int* __restrict__ afe,
                                                int* __restrict__ matched,
                                                int* __restrict__ remain) {
    __shared__ int keyA[4096], valA[4096], keyE[4096];
    __shared__ int ssum[1024];
    const int t = threadIdx.x;
#pragma unroll
    for (int i = 0; i < 4; ++i) { keyA[t + i * 1024] = -1; keyE[t + i * 1024] = -1; }
    __syncthreads();
    // insert both tables
#pragma unroll
    for (int i = 0; i < 2; ++i) {
        int a = t + i * 1024;
        int p = pos_agent[a];
        u32 h = ((u32)p * 2654435761u) >> 20;
        while (true) {
            int prev = atomicCAS(&keyA[h], -1, p);
            if (prev == -1) { valA[h] = a; break; }
            h = (h + 1) & 4095;
        }
        int pe = pos_ego[a];
        u32 he = ((u32)pe * 2654435761u) >> 20;
        while (true) {
            int prev = atomicCAS(&keyE[he], -1, pe);
            if (prev == -1) break;
            he = (he + 1) & 4095;
        }
    }
    __syncthreads();
    // probe ego -> agent (afe, matched)
#pragma unroll
    for (int i = 0; i < 2; ++i) {
        int e = t + i * 1024;
        int p = pos_ego[e];
        u32 h = ((u32)p * 2654435761u) >> 20;
        int idx = 0, fnd = 0;
        while (true) {
            int k = keyA[h];
            if (k == p) { idx = valA[h]; fnd = 1; break; }
            if (k == -1) break;
            h = (h + 1) & 4095;
        }
        afe[e] = idx;
        matched[e] = fnd;
    }
    // probe agent -> ego for flags (contiguous pair per thread for scan order)
    int f[2];
#pragma unroll
    for (int i = 0; i < 2; ++i) {
        int a = t * 2 + i;
        int p = pos_agent[a];
        u32 h = ((u32)p * 2654435761u) >> 20;
        int fnd = 0;
        while (true) {
            int k = keyE[h];
            if (k == p) { fnd = 1; break; }
            if (k == -1) break;
            h = (h + 1) & 4095;
        }
        f[i] = !fnd;
    }
    int cnt = f[0] + f[1];
    ssum[t] = cnt;
    __syncthreads();
    for (int off = 1; off < 1024; off <<= 1) {
        int v = (t >= off) ? ssum[t - off] : 0;
        __syncthreads();
        ssum[t] += v;
        __syncthreads();
    }
    int pos = ssum[t] - cnt;  // exclusive prefix
    if (f[0]) { if (pos < NREM) remain[pos] = t * 2; pos++; }
    if (f[1]) { if (pos < NREM) remain[pos] = t * 2 + 1; }
}

// ------------------------- generic GEMM: A bf16, B fp32 (inline pack) ------
// C[m,n] = A[m,:].B[n,:] + bias[n]; EPI: 0=f32 out, 1=bf16 out
template <int EPI, bool RELU>
__global__ __launch_bounds__(256) void gemm_bw(const u16* __restrict__ A,
                                               const float* __restrict__ B,
                                               const float* __restrict__ bias,
                                               void* __restrict__ C,
                                               int M, int N, int K) {
    const int tid = threadIdx.x;
    const int w = tid >> 6, lane = tid & 63;
    const int quad = lane >> 4, qi = lane & 15;
    const int wm = w >> 1, wn = w & 1;
    const int bm = blockIdx.y * 64, bn = blockIdx.x * 64;

    const u16* pa0 = A + (size_t)(bm + wm * 32 + qi) * K + quad * 8;
    const u16* pa1 = pa0 + (size_t)16 * K;
    const float* pb0 = B + (size_t)(bn + wn * 32 + qi) * K + quad * 8;
    const float* pb1 = pb0 + (size_t)16 * K;

    f32x4 acc00 = {0.f, 0.f, 0.f, 0.f}, acc01 = {0.f, 0.f, 0.f, 0.f};
    f32x4 acc10 = {0.f, 0.f, 0.f, 0.f}, acc11 = {0.f, 0.f, 0.f, 0.f};

#pragma unroll 4
    for (int k = 0; k < K; k += 32) {
        bf16x8 a0 = *(const bf16x8*)(pa0 + k);
        bf16x8 a1 = *(const bf16x8*)(pa1 + k);
        bf16x8 b0 = pk8(pb0 + k);
        bf16x8 b1 = pk8(pb1 + k);
        acc00 = __builtin_amdgcn_mfma_f32_16x16x32_bf16(a0, b0, acc00, 0, 0, 0);
        acc01 = __builtin_amdgcn_mfma_f32_16x16x32_bf16(a0, b1, acc01, 0, 0, 0);
        acc10 = __builtin_amdgcn_mfma_f32_16x16x32_bf16(a1, b0, acc10, 0, 0, 0);
        acc11 = __builtin_amdgcn_mfma_f32_16x16x32_bf16(a1, b1, acc11, 0, 0, 0);
    }

#pragma unroll
    for (int i = 0; i < 2; ++i) {
#pragma unroll
        for (int j = 0; j < 2; ++j) {
            f32x4 acc = (i == 0) ? (j == 0 ? acc00 : acc01) : (j == 0 ? acc10 : acc11);
            int n = bn + wn * 32 + j * 16 + qi;
            int mbase = bm + wm * 32 + i * 16 + quad * 4;
            float bs = bias[n];
#pragma unroll
            for (int r = 0; r < 4; ++r) {
                float x = acc[r] + bs;
                if (RELU) x = fmaxf(x, 0.f);
                if (EPI == 0) ((float*)C)[(size_t)(mbase + r) * N + n] = x;
                else ((u16*)C)[(size_t)(mbase + r) * N + n] = bf16_1(x);
            }
        }
    }
}

// ---------------- MLP layer 1: A = concat(x_ego, x_agent[afe]) fp32 --------
__global__ __launch_bounds__(256) void k_mlp1(const float* __restrict__ x_ego,
                                              const float* __restrict__ x_agent,
                                              const int* __restrict__ afe,
                                              const float* __restrict__ Wf1,
                                              const float* __restrict__ bf1,
                                              u16* __restrict__ h1_b) {
    const int tid = threadIdx.x;
    const int w = tid >> 6, lane = tid & 63;
    const int quad = lane >> 4, qi = lane & 15;
    const int wm = w >> 1, wn = w & 1;
    const int bm = blockIdx.y * 64, bn = blockIdx.x * 64;

    int e0 = bm + wm * 32 + qi, e1 = e0 + 16;
    const float* pe0 = x_ego + (size_t)e0 * CDIM + quad * 8;
    const float* pe1 = x_ego + (size_t)e1 * CDIM + quad * 8;
    const float* pg0 = x_agent + (size_t)afe[e0] * CDIM + quad * 8;
    const float* pg1 = x_agent + (size_t)afe[e1] * CDIM + quad * 8;
    const float* pb0 = Wf1 + (size_t)(bn + wn * 32 + qi) * 512 + quad * 8;
    const float* pb1 = pb0 + (size_t)16 * 512;

    f32x4 acc00 = {0.f, 0.f, 0.f, 0.f}, acc01 = {0.f, 0.f, 0.f, 0.f};
    f32x4 acc10 = {0.f, 0.f, 0.f, 0.f}, acc11 = {0.f, 0.f, 0.f, 0.f};

#pragma unroll 4
    for (int k = 0; k < 256; k += 32) {
        bf16x8 a0 = pk8(pe0 + k);
        bf16x8 a1 = pk8(pe1 + k);
        bf16x8 b0 = pk8(pb0 + k);
        bf16x8 b1 = pk8(pb1 + k);
        acc00 = __builtin_amdgcn_mfma_f32_16x16x32_bf16(a0, b0, acc00, 0, 0, 0);
        acc01 = __builtin_amdgcn_mfma_f32_16x16x32_bf16(a0, b1, acc01, 0, 0, 0);
        acc10 = __builtin_amdgcn_mfma_f32_16x16x32_bf16(a1, b0, acc10, 0, 0, 0);
        acc11 = __builtin_amdgcn_mfma_f32_16x16x32_bf16(a1, b1, acc11, 0, 0, 0);
    }
#pragma unroll 4
    for (int k = 0; k < 256; k += 32) {
        bf16x8 a0 = pk8(pg0 + k);
        bf16x8 a1 = pk8(pg1 + k);
        bf16x8 b0 = pk8(pb0 + 256 + k);
        bf16x8 b1 = pk8(pb1 + 256 + k);
        acc00 = __builtin_amdgcn_mfma_f32_16x16x32_bf16(a0, b0, acc00, 0, 0, 0);
        acc01 = __builtin_amdgcn_mfma_f32_16x16x32_bf16(a0, b1, acc01, 0, 0, 0);
        acc10 = __builtin_amdgcn_mfma_f32_16x16x32_bf16(a1, b0, acc10, 0, 0, 0);
        acc11 = __builtin_amdgcn_mfma_f32_16x16x32_bf16(a1, b1, acc11, 0, 0, 0);
    }

#pragma unroll
    for (int i = 0; i < 2; ++i) {
#pragma unroll
        for (int j = 0; j < 2; ++j) {
            f32x4 acc = (i == 0) ? (j == 0 ? acc00 : acc01) : (j == 0 ? acc10 : acc11);
            int n = bn + wn * 32 + j * 16 + qi;
            int mbase = bm + wm * 32 + i * 16 + quad * 4;
            float bs = bf1[n];
#pragma unroll
            for (int r = 0; r < 4; ++r)
                h1_b[(size_t)(mbase + r) * 256 + n] = bf16_1(fmaxf(acc[r] + bs, 0.f));
        }
    }
}

// ------- MLP layer 3 + finalize: qbuf = select(matched, mlp, x_ego) --------
// grid (4, 48). by<32: GEMM rows; by>=32: gather x_agent[remain] rows.
__global__ __launch_bounds__(256) void k_mlp3f(const u16* __restrict__ h2_b,
                                               const float* __restrict__ Wf3,
                                               const float* __restrict__ bf3,
                                               const int* __restrict__ matched,
                                               const int* __restrict__ remain,
                                               const float* __restrict__ x_ego,
                                               const float* __restrict__ x_agent,
                                               float* __restrict__ qbuf,
                                               u16* __restrict__ qbuf_b) {
    const int tid = threadIdx.x;
    const int bm = blockIdx.y * 64, bn = blockIdx.x * 64;
    if (bm >= LE) {
        // gather: 64 rows x 64 cols; 4 threads/row, 16 cols each
        int row = bm + (tid >> 2);
        int col = bn + (tid & 3) * 16;
        int idx = remain[row - LE];
        idx = min(max(idx, 0), LA - 1);
        const float* src = x_agent + (size_t)idx * CDIM + col;
        float* dq = qbuf + (size_t)row * CDIM + col;
        u16* db = qbuf_b + (size_t)row * CDIM + col;
#pragma unroll
        for (int i = 0; i < 4; ++i) {
            float4 v = *(const float4*)(src + i * 4);
            *(float4*)(dq + i * 4) = v;
            u32 p0 = pk_bf16(v.x, v.y), p1 = pk_bf16(v.z, v.w);
            *(uint2*)(db + i * 4) = make_uint2(p0, p1);
        }
        return;
    }
    const int w = tid >> 6, lane = tid & 63;
    const int quad = lane >> 4, qi = lane & 15;
    const int wm = w >> 1, wn = w & 1;

    const u16* pa0 = h2_b + (size_t)(bm + wm * 32 + qi) * 256 + quad * 8;
    const u16* pa1 = pa0 + (size_t)16 * 256;
    const float* pb0 = Wf3 + (size_t)(bn + wn * 32 + qi) * 256 + quad * 8;
    const float* pb1 = pb0 + (size_t)16 * 256;

    f32x4 acc00 = {0.f, 0.f, 0.f, 0.f}, acc01 = {0.f, 0.f, 0.f, 0.f};
    f32x4 acc10 = {0.f, 0.f, 0.f, 0.f}, acc11 = {0.f, 0.f, 0.f, 0.f};
#pragma unroll 4
    for (int k = 0; k < 256; k += 32) {
        bf16x8 a0 = *(const bf16x8*)(pa0 + k);
        bf16x8 a1 = *(const bf16x8*)(pa1 + k);
        bf16x8 b0 = pk8(pb0 + k);
        bf16x8 b1 = pk8(pb1 + k);
        acc00 = __builtin_amdgcn_mfma_f32_16x16x32_bf16(a0, b0, acc00, 0, 0, 0);
        acc01 = __builtin_amdgcn_mfma_f32_16x16x32_bf16(a0, b1, acc01, 0, 0, 0);
        acc10 = __builtin_amdgcn_mfma_f32_16x16x32_bf16(a1, b0, acc10, 0, 0, 0);
        acc11 = __builtin_amdgcn_mfma_f32_16x16x32_bf16(a1, b1, acc11, 0, 0, 0);
    }
#pragma unroll
    for (int i = 0; i < 2; ++i) {
#pragma unroll
        for (int j = 0; j < 2; ++j) {
            f32x4 acc = (i == 0) ? (j == 0 ? acc00 : acc01) : (j == 0 ? acc10 : acc11);
            int n = bn + wn * 32 + j * 16 + qi;
            int mbase = bm + wm * 32 + i * 16 + quad * 4;
            float bs = bf3[n];
#pragma unroll
            for (int r = 0; r < 4; ++r) {
                int row = mbase + r;
                float v = acc[r] + bs;
                if (!matched[row]) v = x_ego[(size_t)row * CDIM + n];
                qbuf[(size_t)row * CDIM + n] = v;
                qbuf_b[(size_t)row * CDIM + n] = bf16_1(v);
            }
        }
    }
}

// --------------------------- fused QKV projection (one dispatch) -----------
// blocks [0,192): Q = qbuf_b @ Wq^T * qscale -> qb
// blocks [192,704): KV = concat(x_ego,x_agent) @ Wkv^T; n<256 -> kb; else vtb^T
__global__ __launch_bounds__(256) void k_qkv(const u16* __restrict__ qbuf_b,
                                             const float* __restrict__ x_ego,
                                             const float* __restrict__ x_agent,
                                             const float* __restrict__ Wqkv,
                                             const float* __restrict__ bqkv,
                                             u16* __restrict__ qb,
                                             u16* __restrict__ kbp,
                                             u16* __restrict__ vtb,
                                             float qscale) {
    int b = blockIdx.x;
    const int tid = threadIdx.x;
    const int w = tid >> 6, lane = tid & 63;
    const int quad = lane >> 4, qi = lane & 15;
    const int wm = w >> 1, wn = w & 1;

    f32x4 acc00 = {0.f, 0.f, 0.f, 0.f}, acc01 = {0.f, 0.f, 0.f, 0.f};
    f32x4 acc10 = {0.f, 0.f, 0.f, 0.f}, acc11 = {0.f, 0.f, 0.f, 0.f};

    if (b < 192) {
        const int bm = (b >> 2) * 64, bn = (b & 3) * 64;
        const u16* pa0 = qbuf_b + (size_t)(bm + wm * 32 + qi) * 256 + quad * 8;
        const u16* pa1 = pa0 + (size_t)16 * 256;
        const float* pb0 = Wqkv + (size_t)(bn + wn * 32 + qi) * 256 + quad * 8;
        const float* pb1 = pb0 + (size_t)16 * 256;
#pragma unroll 4
        for (int k = 0; k < 256; k += 32) {
            bf16x8 a0 = *(const bf16x8*)(pa0 + k);
            bf16x8 a1 = *(const bf16x8*)(pa1 + k);
            bf16x8 b0 = pk8(pb0 + k);
            bf16x8 b1 = pk8(pb1 + k);
            acc00 = __builtin_amdgcn_mfma_f32_16x16x32_bf16(a0, b0, acc00, 0, 0, 0);
            acc01 = __builtin_amdgcn_mfma_f32_16x16x32_bf16(a0, b1, acc01, 0, 0, 0);
            acc10 = __builtin_amdgcn_mfma_f32_16x16x32_bf16(a1, b0, acc10, 0, 0, 0);
            acc11 = __builtin_amdgcn_mfma_f32_16x16x32_bf16(a1, b1, acc11, 0, 0, 0);
        }
#pragma unroll
        for (int i = 0; i < 2; ++i)
#pragma unroll
            for (int j = 0; j < 2; ++j) {
                f32x4 acc = (i == 0) ? (j == 0 ? acc00 : acc01) : (j == 0 ? acc10 : acc11);
                int n = bn + wn * 32 + j * 16 + qi;
                int mbase = bm + wm * 32 + i * 16 + quad * 4;
                float bs = bqkv[n];
#pragma unroll
                for (int r = 0; r < 4; ++r)
                    qb[(size_t)(mbase + r) * 256 + n] = bf16_1((acc[r] + bs) * qscale);
            }
    } else {
        int c = b - 192;
        const int bm = (c >> 3) * 64, bn = (c & 7) * 64;
        int j0 = bm + wm * 32 + qi, j1 = j0 + 16;
        const float* base = (bm < LE) ? x_ego : (x_agent - (size_t)LE * CDIM);
        const float* pa0 = base + (size_t)j0 * CDIM + quad * 8;
        const float* pa1 = base + (size_t)j1 * CDIM + quad * 8;
        const float* pb0 = Wqkv + (size_t)(256 + bn + wn * 32 + qi) * 256 + quad * 8;
        const float* pb1 = pb0 + (size_t)16 * 256;
#pragma unroll 4
        for (int k = 0; k < 256; k += 32) {
            bf16x8 a0 = pk8(pa0 + k);
            bf16x8 a1 = pk8(pa1 + k);
            bf16x8 b0 = pk8(pb0 + k);
            bf16x8 b1 = pk8(pb1 + k);
            acc00 = __builtin_amdgcn_mfma_f32_16x16x32_bf16(a0, b0, acc00, 0, 0, 0);
            acc01 = __builtin_amdgcn_mfma_f32_16x16x32_bf16(a0, b1, acc01, 0, 0, 0);
            acc10 = __builtin_amdgcn_mfma_f32_16x16x32_bf16(a1, b0, acc10, 0, 0, 0);
            acc11 = __builtin_amdgcn_mfma_f32_16x16x32_bf16(a1, b1, acc11, 0, 0, 0);
        }
#pragma unroll
        for (int i = 0; i < 2; ++i)
#pragma unroll
            for (int j = 0; j < 2; ++j) {
                f32x4 acc = (i == 0) ? (j == 0 ? acc00 : acc01) : (j == 0 ? acc10 : acc11);
                int n = bn + wn * 32 + j * 16 + qi;
                int mbase = bm + wm * 32 + i * 16 + quad * 4;
                float bs = bqkv[256 + n];
                float v[4];
#pragma unroll
                for (int r = 0; r < 4; ++r) v[r] = acc[r] + bs;
                if (n < 256) {
#pragma unroll
                    for (int r = 0; r < 4; ++r)
                        kbp[(size_t)(mbase + r) * 256 + n] = bf16_1(v[r]);
                } else {
                    ushort4 o4;
                    o4.x = bf16_1(v[0]); o4.y = bf16_1(v[1]);
                    o4.z = bf16_1(v[2]); o4.w = bf16_1(v[3]);
                    *(ushort4*)(vtb + (size_t)(n - 256) * LKC + mbase) = o4;
                }
            }
    }
}

// --------------------------- MFMA attention, LDS-staged K/V tiles ----------
__global__ __launch_bounds__(256) void attn_mfma(const u16* __restrict__ qb,
                                                 const u16* __restrict__ kb,
                                                 const u16* __restrict__ vtb,
                                                 float* __restrict__ Pl,
                                                 float* __restrict__ Pacc) {
    __shared__ u16 Kt[2][64 * 32];
    __shared__ u16 Vt[2][32 * 64];
    __shared__ u16 plds[4][16 * 64];
    const int tid = threadIdx.x;
    const int w = tid >> 6, lane = tid & 63;
    const int quad = lane >> 4, qi = lane & 15;
    const int h = blockIdx.y, ks = blockIdx.z;
    const int q0 = blockIdx.x * 64 + w * 16;

    bf16x8 qf = *(const bf16x8*)(qb + (size_t)(q0 + qi) * CDIM + h * DH + quad * 8);

    f32x4 O0 = {0.f, 0.f, 0.f, 0.f}, O1 = {0.f, 0.f, 0.f, 0.f};
    float lsum = 0.f;

    const int krow = w * 16 + (lane >> 2), kcp = lane & 3;
    const int kc = kcp ^ (krow & 3);
    const u16* kg0 = kb + (size_t)krow * CDIM + h * DH + kc * 8;
    const int kdst = krow * 32 + kcp * 8;
    const int vd = w * 8 + (lane >> 3), vcp = lane & 7;
    const int vc = vcp ^ (vd & 7);
    const u16* vg0 = vtb + (size_t)(h * DH + vd) * LKC + vc * 8;
    const int vdst = vd * 64 + vcp * 8;

    const int ka0 = qi * 32 + ((quad ^ (qi & 3)) << 3);
    const int v00o = qi * 64 + ((quad ^ (qi & 7)) << 3);
    const int v01o = qi * 64 + (((quad + 4) ^ (qi & 7)) << 3);
    const int swz = (qi & 7);
    const int rd0 = qi * 64 + ((quad ^ swz) << 3);
    const int rd1 = qi * 64 + (((4 + quad) ^ swz) << 3);
    const int half = (quad & 1) << 2;

    int kt = ks * (LKC / KSPLIT);
    {
        bf16x8 kr = *(const bf16x8*)(kg0 + (size_t)kt * CDIM);
        bf16x8 vr = *(const bf16x8*)(vg0 + kt);
        *(bf16x8*)&Kt[0][kdst] = kr;
        *(bf16x8*)&Vt[0][vdst] = vr;
    }
    int buf = 0;
    for (int it = 0; it < NIT; ++it, kt += 64) {
        __syncthreads();
        bf16x8 knext, vnext;
        const bool more = (it + 1 < NIT);
        if (more) {
            knext = *(const bf16x8*)(kg0 + (size_t)(kt + 64) * CDIM);
            vnext = *(const bf16x8*)(vg0 + kt + 64);
        }

        bf16x8 a0 = *(const bf16x8*)&Kt[buf][ka0];
        bf16x8 a1 = *(const bf16x8*)&Kt[buf][ka0 + 16 * 32];
        bf16x8 a2 = *(const bf16x8*)&Kt[buf][ka0 + 32 * 32];
        bf16x8 a3 = *(const bf16x8*)&Kt[buf][ka0 + 48 * 32];
        f32x4 z = {0.f, 0.f, 0.f, 0.f};
        f32x4 s0 = __builtin_amdgcn_mfma_f32_16x16x32_bf16(a0, qf, z, 0, 0, 0);
        f32x4 s1 = __builtin_amdgcn_mfma_f32_16x16x32_bf16(a1, qf, z, 0, 0, 0);
        f32x4 s2 = __builtin_amdgcn_mfma_f32_16x16x32_bf16(a2, qf, z, 0, 0, 0);
        f32x4 s3 = __builtin_amdgcn_mfma_f32_16x16x32_bf16(a3, qf, z, 0, 0, 0);

        float p0[4], p1[4], p2[4], p3[4];
#pragma unroll
        for (int r = 0; r < 4; ++r) {
            p0[r] = fast_exp2(s0[r]); p1[r] = fast_exp2(s1[r]);
            p2[r] = fast_exp2(s2[r]); p3[r] = fast_exp2(s3[r]);
            lsum += p0[r] + p1[r] + p2[r] + p3[r];
        }

        u16* pb = &plds[w][0];
#pragma unroll
        for (int t = 0; t < 4; ++t) {
            int jg = t * 2 + (quad >> 1);
            int off = qi * 64 + ((jg ^ swz) << 3) + half;
            uint2 pw;
            float* pp = (t == 0) ? p0 : (t == 1) ? p1 : (t == 2) ? p2 : p3;
            pw.x = pk_bf16(pp[0], pp[1]);
            pw.y = pk_bf16(pp[2], pp[3]);
            *(uint2*)&pb[off] = pw;
        }
        bf16x8 pa0 = *(bf16x8*)&pb[rd0];
        bf16x8 pa1 = *(bf16x8*)&pb[rd1];

        bf16x8 v00 = *(const bf16x8*)&Vt[buf][v00o];
        bf16x8 v01 = *(const bf16x8*)&Vt[buf][v01o];
        bf16x8 v10 = *(const bf16x8*)&Vt[buf][v00o + 16 * 64];
        bf16x8 v11 = *(const bf16x8*)&Vt[buf][v01o + 16 * 64];
        O0 = __builtin_amdgcn_mfma_f32_16x16x32_bf16(pa0, v00, O0, 0, 0, 0);
        O0 = __builtin_amdgcn_mfma_f32_16x16x32_bf16(pa1, v01, O0, 0, 0, 0);
        O1 = __builtin_amdgcn_mfma_f32_16x16x32_bf16(pa0, v10, O1, 0, 0, 0);
        O1 = __builtin_amdgcn_mfma_f32_16x16x32_bf16(pa1, v11, O1, 0, 0, 0);

        if (more) {
            *(bf16x8*)&Kt[buf ^ 1][kdst] = knext;
            *(bf16x8*)&Vt[buf ^ 1][vdst] = vnext;
        }
        buf ^= 1;
    }

    lsum += __shfl_xor(lsum, 16, 64);
    lsum += __shfl_xor(lsum, 32, 64);

    int pbase = (h * KSPLIT + ks) * LQC + q0;
    if (quad == 0) Pl[pbase + qi] = lsum;
#pragma unroll
    for (int r = 0; r < 4; ++r) {
        int q = quad * 4 + r;
        float* pa = Pacc + (size_t)(pbase + q) * 32;
        pa[qi] = O0[r];
        pa[16 + qi] = O1[r];
    }
}

__global__ __launch_bounds__(256) void attn_combine(const float* __restrict__ Pl,
                                                    const float* __restrict__ Pacc,
                                                    u16* __restrict__ attn_b) {
    int t = blockIdx.x * 256 + threadIdx.x;  // LQC*64
    int row = t >> 6;
    int h = (t >> 3) & 7;
    int d4 = t & 7;
    float L = 0.f;
    float o[4] = {};
#pragma unroll
    for (int ck = 0; ck < KSPLIT; ++ck) {
        size_t pidx = (size_t)(h * KSPLIT + ck) * LQC + row;
        L += Pl[pidx];
        float4 a = *(const float4*)(Pacc + pidx * 32 + d4 * 4);
        o[0] += a.x; o[1] += a.y; o[2] += a.z; o[3] += a.w;
    }
    float inv = 1.0f / L;
    ushort4 ov;
    ov.x = bf16_1(o[0] * inv); ov.y = bf16_1(o[1] * inv);
    ov.z = bf16_1(o[2] * inv); ov.w = bf16_1(o[3] * inv);
    *(ushort4*)(attn_b + (size_t)row * CDIM + h * DH + d4 * 4) = ov;
}

// -------------------------------------------------------------- layernorm --
template <bool EMIT_BF16>
__global__ __launch_bounds__(256) void ln_kernel(const float* __restrict__ X,
                                                 const float* __restrict__ R,
                                                 const float* __restrict__ g,
                                                 const float* __restrict__ b,
                                                 float* __restrict__ out,
                                                 u16* __restrict__ out_b) {
    int lane = threadIdx.x & 63;
    int row = blockIdx.x * 4 + (threadIdx.x >> 6);
    const float* x = X + (size_t)row * CDIM;
    const float* r = R + (size_t)row * CDIM;
    float4 xv = *(const float4*)(x + lane * 4);
    float4 rv = *(const float4*)(r + lane * 4);
    float v[4] = {xv.x + rv.x, xv.y + rv.y, xv.z + rv.z, xv.w + rv.w};
    float s = v[0] + v[1] + v[2] + v[3];
    float sq = v[0] * v[0] + v[1] * v[1] + v[2] * v[2] + v[3] * v[3];
#pragma unroll
    for (int off = 32; off >= 1; off >>= 1) {
        s += __shfl_xor(s, off, 64);
        sq += __shfl_xor(sq, off, 64);
    }
    float mean = s * (1.f / 256.f);
    float var = sq * (1.f / 256.f) - mean * mean;
    float rstd = rsqrtf(var + 1e-5f);
    float4 gv = *(const float4*)(g + lane * 4);
    float4 bv = *(const float4*)(b + lane * 4);
    float4 o = make_float4((v[0] - mean) * rstd * gv.x + bv.x,
                           (v[1] - mean) * rstd * gv.y + bv.y,
                           (v[2] - mean) * rstd * gv.z + bv.z,
                           (v[3] - mean) * rstd * gv.w + bv.w);
    *(float4*)(out + (size_t)row * CDIM + lane * 4) = o;
    if (EMIT_BF16) {
        uint2 ob;
        ob.x = pk_bf16(o.x, o.y);
        ob.y = pk_bf16(o.z, o.w);
        *(uint2*)(out_b + (size_t)row * CDIM + lane * 4) = ob;
    }
}

// ------------------------------------------------------------------ launch --
extern "C" void kernel_launch(void* const* d_in, const int* in_sizes, int n_in,
                              void* d_out, int out_size, void* d_ws, size_t ws_size,
                              hipStream_t stream) {
    const float* x_ego = (const float*)d_in[0];
    const float* x_agent = (const float*)d_in[1];
    const float* Wf1 = (const float*)d_in[2];
    const float* bf1 = (const float*)d_in[3];
    const float* Wf2 = (const float*)d_in[4];
    const float* bf2 = (const float*)d_in[5];
    const float* Wf3 = (const float*)d_in[6];
    const float* bf3 = (const float*)d_in[7];
    const float* Wqkv = (const float*)d_in[8];
    const float* bqkv = (const float*)d_in[9];
    const float* Wo = (const float*)d_in[10];
    const float* bo = (const float*)d_in[11];
    const float* W1 = (const float*)d_in[12];
    const float* b1 = (const float*)d_in[13];
    const float* W2 = (const float*)d_in[14];
    const float* b2 = (const float*)d_in[15];
    const float* g1 = (const float*)d_in[16];
    const float* be1 = (const float*)d_in[17];
    const float* g2 = (const float*)d_in[18];
    const float* be2 = (const float*)d_in[19];
    const int* pos_ego = (const int*)d_in[20];
    const int* pos_agent = (const int*)d_in[21];

    float* ws = (float*)d_ws;
    size_t o = 0;
    float* qbuf = ws + o; o += 786432;
    float* o2 = ws + o; o += 786432;
    float* yq = ws + o; o += 786432;
    float* ff2 = ws + o; o += 786432;
    float* Pl = ws + o; o += HN * KSPLIT * LQC;
    float* Pacc = ws + o; o += (size_t)HN * KSPLIT * LQC * 32;
    u16* h1_b = (u16*)(ws + o); o += 262144;     // LE*256
    u16* h2_b = (u16*)(ws + o); o += 262144;
    u16* qbuf_b = (u16*)(ws + o); o += 393216;   // LQC*256
    u16* qb = (u16*)(ws + o); o += 393216;
    u16* kb = (u16*)(ws + o); o += 524288;       // LKC*256
    u16* vtb = (u16*)(ws + o); o += 524288;
    u16* attn_b = (u16*)(ws + o); o += 393216;
    u16* ff1_b = (u16*)(ws + o); o += 1572864;   // LQC*1024
    u16* yq_b = (u16*)(ws + o); o += 393216;
    int* afe = (int*)(ws + o);
    int* matched = afe + LE;
    int* remain = matched + LE;

    const float qscale = 0.17677669529663687f * 1.4426950408889634f;

    // 1. matching (hash join + scan, one block)
    k_match<<<1, 1024, 0, stream>>>(pos_ego, pos_agent, afe, matched, remain);

    // 2-4. fusion MLP (inline fp32 pack for inputs & weights)
    k_mlp1<<<dim3(4, 32), 256, 0, stream>>>(x_ego, x_agent, afe, Wf1, bf1, h1_b);
    gemm_bw<1, true><<<dim3(4, 32), 256, 0, stream>>>(h1_b, Wf2, bf2, h2_b, LE, 256, 256);
    k_mlp3f<<<dim3(4, 48), 256, 0, stream>>>(h2_b, Wf3, bf3, matched, remain,
                                             x_ego, x_agent, qbuf, qbuf_b);

    // 5. fused QKV projections (KV input read from x directly)
    k_qkv<<<704, 256, 0, stream>>>(qbuf_b, x_ego, x_agent, Wqkv, bqkv, qb, kb, vtb, qscale);

    // 6-7. attention
    attn_mfma<<<dim3(LQC / 64, HN, KSPLIT), 256, 0, stream>>>(qb, kb, vtb, Pl, Pacc);
    attn_combine<<<(LQC * 64) / 256, 256, 0, stream>>>(Pl, Pacc, attn_b);

    // 8-9. out-proj + LN1
    gemm_bw<0, false><<<dim3(4, 48), 256, 0, stream>>>(attn_b, Wo, bo, o2, LQC, 256, 256);
    ln_kernel<true><<<LQC / 4, 256, 0, stream>>>(qbuf, o2, g1, be1, yq, yq_b);

    // 10-12. FFN + LN2
    gemm_bw<1, true><<<dim3(16, 48), 256, 0, stream>>>(yq_b, W1, b1, ff1_b, LQC, DFF, 256);
    gemm_bw<0, false><<<dim3(4, 48), 256, 0, stream>>>(ff1_b, W2, b2, ff2, LQC, 256, DFF);
    ln_kernel<false><<<LQC / 4, 256, 0, stream>>>(yq, ff2, g2, be2, (float*)d_out, nullptr);
}